// Round 1
// baseline (670.250 us; speedup 1.0000x reference)
//
#include <hip/hip_runtime.h>
#include <math.h>

#define BB 4
#define NXD 512
#define NYD 512
#define DVD 32
#define KXD 64
#define KYD 64

// workspace layout (float offsets)
#define OFF_DN  0            // DtabN [64][512]
#define OFF_DT  32768        // DtabT [512][64]
#define OFF_FCN 65536        // FtcN  [64][512]
#define OFF_FSN 98304        // FtsN  [64][512]
#define OFF_FCT 131072       // FtcT  [512][64]
#define OFF_FST 163840       // FtsT  [512][64]
#define OFF_C   196608       // C  [4][64ky][512nx][32dv]
#define OFF_FR  4390912      // Fr [4][64ky][64kx][32j]
#define OFF_FI  4915200
#define OFF_YR  5439488      // Yr [4][32i][64kx][64ky]
#define OFF_YI  5963776
#define OFF_G   6488064      // G  [4][512nx][32i][64ky]
// total = 10,682,368 floats = 42.7 MB

__global__ __launch_bounds__(256) void k_tables(float* __restrict__ ws) {
    int idx = blockIdx.x * 256 + threadIdx.x;   // 0..32767
    int k = idx >> 9;                            // 0..63
    int n = idx & 511;                           // 0..511
    const float inv_sq512 = 0.04419417382415922f;  // 1/sqrt(512)
    // DCT-II ortho basis: a_k * cos(pi*k*(2n+1)/1024), exact reduction mod 2048
    float ak = (k == 0) ? inv_sq512 : 0.0625f;   // sqrt(2/512)=1/16
    int m = (k * (2 * n + 1)) & 2047;
    float d = ak * cospif((float)m * (1.0f / 1024.0f));
    ws[OFF_DN + k * 512 + n] = d;
    ws[OFF_DT + n * 64 + k] = d;
    // FFT twiddles cos/sin(2*pi*k*n/512)/sqrt(512), exact reduction mod 512
    int mf = (k * n) & 511;
    float c = cospif((float)mf * (1.0f / 256.0f)) * inv_sq512;
    float s = sinpif((float)mf * (1.0f / 256.0f)) * inv_sq512;
    ws[OFF_FCN + k * 512 + n] = c;
    ws[OFF_FSN + k * 512 + n] = s;
    ws[OFF_FCT + n * 64 + k] = c;
    ws[OFF_FST + n * 64 + k] = s;
}

// K1: DCT along NY, truncated to 64 coeffs.  block = (b,nx)
__global__ __launch_bounds__(256) void k_dct(const float* __restrict__ x,
                                             const float* __restrict__ ws,
                                             float* __restrict__ C) {
    __shared__ __align__(16) float xs[NYD * DVD];   // 64 KB [ny][dv]
    int b = blockIdx.x >> 9;
    int nx = blockIdx.x & 511;
    int t = threadIdx.x;
    const float4* src = (const float4*)(x + (size_t)(b * NXD + nx) * NYD * DVD);
    float4* dst4 = (float4*)xs;
#pragma unroll
    for (int p = 0; p < 16; ++p) dst4[p * 256 + t] = src[p * 256 + t];
    __syncthreads();
    int dv0 = (t & 15) * 2;
    int ky0 = (t >> 4) * 4;
    const float* Dt = ws + OFF_DT;   // [ny][64]
    float a00 = 0, a01 = 0, a10 = 0, a11 = 0, a20 = 0, a21 = 0, a30 = 0, a31 = 0;
#pragma unroll 4
    for (int ny = 0; ny < NYD; ++ny) {
        float2 xv = *(const float2*)(xs + ny * DVD + dv0);
        float4 d4 = *(const float4*)(Dt + ny * 64 + ky0);
        a00 += d4.x * xv.x; a01 += d4.x * xv.y;
        a10 += d4.y * xv.x; a11 += d4.y * xv.y;
        a20 += d4.z * xv.x; a21 += d4.z * xv.y;
        a30 += d4.w * xv.x; a31 += d4.w * xv.y;
    }
    float2 v;
    float* base = C + ((size_t)((b * KYD + ky0) * NXD + nx)) * DVD + dv0;
    size_t kystride = (size_t)NXD * DVD;
    v.x = a00; v.y = a01; *(float2*)(base) = v;
    v.x = a10; v.y = a11; *(float2*)(base + kystride) = v;
    v.x = a20; v.y = a21; *(float2*)(base + 2 * kystride) = v;
    v.x = a30; v.y = a31; *(float2*)(base + 3 * kystride) = v;
}

// K2: truncated rFFT along NX.  block = (b,ky)
__global__ __launch_bounds__(256) void k_rfft(const float* __restrict__ Cbuf,
                                              const float* __restrict__ ws,
                                              float* __restrict__ Fr,
                                              float* __restrict__ Fi) {
    __shared__ __align__(16) float cs[NXD * DVD];   // 64 KB [nx][dv]
    int b = blockIdx.x >> 6;
    int ky = blockIdx.x & 63;
    int t = threadIdx.x;
    const float4* src = (const float4*)(Cbuf + (size_t)(b * KYD + ky) * NXD * DVD);
    float4* dst4 = (float4*)cs;
#pragma unroll
    for (int p = 0; p < 16; ++p) dst4[p * 256 + t] = src[p * 256 + t];
    __syncthreads();
    int dv0 = (t & 15) * 2;
    int kx0 = (t >> 4) * 4;
    const float* Tc = ws + OFF_FCT;
    const float* Ts = ws + OFF_FST;
    float ar[4][2] = {}, ai[4][2] = {};
#pragma unroll 4
    for (int nx = 0; nx < NXD; ++nx) {
        float2 cv = *(const float2*)(cs + nx * DVD + dv0);
        float4 c4 = *(const float4*)(Tc + nx * 64 + kx0);
        float4 s4 = *(const float4*)(Ts + nx * 64 + kx0);
        ar[0][0] += c4.x * cv.x; ar[0][1] += c4.x * cv.y;
        ar[1][0] += c4.y * cv.x; ar[1][1] += c4.y * cv.y;
        ar[2][0] += c4.z * cv.x; ar[2][1] += c4.z * cv.y;
        ar[3][0] += c4.w * cv.x; ar[3][1] += c4.w * cv.y;
        ai[0][0] -= s4.x * cv.x; ai[0][1] -= s4.x * cv.y;
        ai[1][0] -= s4.y * cv.x; ai[1][1] -= s4.y * cv.y;
        ai[2][0] -= s4.z * cv.x; ai[2][1] -= s4.z * cv.y;
        ai[3][0] -= s4.w * cv.x; ai[3][1] -= s4.w * cv.y;
    }
#pragma unroll
    for (int q = 0; q < 4; ++q) {
        size_t o = ((size_t)((b * KYD + ky) * KXD + kx0 + q)) * DVD + dv0;
        float2 vr; vr.x = ar[q][0]; vr.y = ar[q][1];
        float2 vi; vi.x = ai[q][0]; vi.y = ai[q][1];
        *(float2*)(Fr + o) = vr;
        *(float2*)(Fi + o) = vi;
    }
}

// K3: channel mix per (kx,ky).  block = (kx, i-quarter); lanes = ky
__global__ __launch_bounds__(256) void k_mix(const float* __restrict__ Rr,
                                             const float* __restrict__ Ri,
                                             const float* __restrict__ Fr,
                                             const float* __restrict__ Fi,
                                             float* __restrict__ Yr,
                                             float* __restrict__ Yi) {
    __shared__ float flr[4 * 32 * 64];   // 32 KB, swizzled [e][j][(ky+j)&63]
    __shared__ float fli[4 * 32 * 64];
    int kx = blockIdx.x & 63;
    int iq = blockIdx.x >> 6;   // 0..3
    int t = threadIdx.x;
    int j = t & 31, kyb = t >> 5;   // kyb 0..7
#pragma unroll
    for (int e = 0; e < 4; ++e) {
#pragma unroll
        for (int p = 0; p < 8; ++p) {
            int ky = p * 8 + kyb;
            size_t go = ((size_t)((e * KYD + ky) * KXD + kx)) * DVD + j;
            int lo = (e * 32 + j) * 64 + ((ky + j) & 63);
            flr[lo] = Fr[go];
            fli[lo] = Fi[go];
        }
    }
    __syncthreads();
    int lane = t & 63, w = t >> 6;
#pragma unroll
    for (int ii = 0; ii < 2; ++ii) {
        int i = iq * 8 + w * 2 + ii;
        float yr[4] = {}, yi[4] = {};
        for (int jj = 0; jj < 32; ++jj) {
            float rr = Rr[(((size_t)i * 32 + jj) * 64 + kx) * 64 + lane];
            float ri = Ri[(((size_t)i * 32 + jj) * 64 + kx) * 64 + lane];
#pragma unroll
            for (int e = 0; e < 4; ++e) {
                int lo = (e * 32 + jj) * 64 + ((lane + jj) & 63);
                float fr = flr[lo];
                float fi = fli[lo];
                yr[e] += rr * fr - ri * fi;
                yi[e] += rr * fi + ri * fr;
            }
        }
#pragma unroll
        for (int e = 0; e < 4; ++e) {
            size_t o = ((size_t)((e * DVD + i) * KXD + kx)) * KYD + lane;
            Yr[o] = yr[e];
            Yi[o] = yi[e];
        }
    }
}

// K4: truncated irFFT along NX.  block = (b, i, nx-half)
__global__ __launch_bounds__(256) void k_irfft(const float* __restrict__ Yr,
                                               const float* __restrict__ Yi,
                                               const float* __restrict__ ws,
                                               float* __restrict__ G) {
    __shared__ __align__(16) float ylr[64 * 64];   // 16 KB [kx][ky], pre-weighted
    __shared__ __align__(16) float yli[64 * 64];
    int blk = blockIdx.x;
    int half = blk & 1;
    int i = (blk >> 1) & 31;
    int b = blk >> 6;
    int t = threadIdx.x;
    size_t ybase = ((size_t)(b * DVD + i)) * KXD * KYD;
#pragma unroll
    for (int p = 0; p < 16; ++p) {
        int idx = p * 256 + t;
        float wk = (idx < 64) ? 1.0f : 2.0f;   // kx==0 weight 1, else 2
        ylr[idx] = Yr[ybase + idx] * wk;
        yli[idx] = Yi[ybase + idx] * wk;
    }
    __syncthreads();
    int kyg = t & 15, nxg = t >> 4;
    int ky0 = kyg * 4;
    const float* Tc = ws + OFF_FCN;   // [kx][nx]
    const float* Ts = ws + OFF_FSN;
    for (int c = 0; c < 4; ++c) {
        int gnx0 = half * 256 + c * 64 + nxg * 4;
        float acc[4][4] = {};
        for (int kx = 0; kx < 64; ++kx) {
            float4 cv = *(const float4*)(Tc + kx * 512 + gnx0);
            float4 sv = *(const float4*)(Ts + kx * 512 + gnx0);
            float4 vr = *(const float4*)(ylr + kx * 64 + ky0);
            float4 vi = *(const float4*)(yli + kx * 64 + ky0);
            float ca[4] = {cv.x, cv.y, cv.z, cv.w};
            float sa[4] = {sv.x, sv.y, sv.z, sv.w};
            float ra[4] = {vr.x, vr.y, vr.z, vr.w};
            float ia[4] = {vi.x, vi.y, vi.z, vi.w};
#pragma unroll
            for (int q = 0; q < 4; ++q)
#pragma unroll
                for (int kk = 0; kk < 4; ++kk)
                    acc[q][kk] += ca[q] * ra[kk] - sa[q] * ia[kk];
        }
#pragma unroll
        for (int q = 0; q < 4; ++q) {
            float4 v; v.x = acc[q][0]; v.y = acc[q][1]; v.z = acc[q][2]; v.w = acc[q][3];
            *(float4*)(G + (((size_t)(b * NXD + gnx0 + q)) * DVD + i) * KYD + ky0) = v;
        }
    }
}

// K5: iDCT along NY.  block = (b,nx)
__global__ __launch_bounds__(256) void k_idct(const float* __restrict__ G,
                                              const float* __restrict__ ws,
                                              float* __restrict__ out) {
    __shared__ __align__(16) float gs[DVD * 68];   // [i][ky] padded to 68
    int b = blockIdx.x >> 9;
    int nx = blockIdx.x & 511;
    int t = threadIdx.x;
    const float* src = G + ((size_t)(b * NXD + nx)) * DVD * KYD;
#pragma unroll
    for (int p = 0; p < 8; ++p) {
        int idx = p * 256 + t;
        gs[(idx >> 6) * 68 + (idx & 63)] = src[idx];
    }
    __syncthreads();
    int ig = t & 15, nyg = t >> 4;
    int i0 = ig * 2;
    const float* Dn = ws + OFF_DN;   // [ky][ny]
    float* outb = out + ((size_t)(b * NXD + nx)) * NYD * DVD;
    for (int c = 0; c < 8; ++c) {
        int ny0 = c * 64 + nyg * 4;
        float acc[4][2] = {};
        for (int kyc = 0; kyc < 16; ++kyc) {
            int ky0 = kyc * 4;
            float4 g0 = *(const float4*)(gs + i0 * 68 + ky0);
            float4 g1 = *(const float4*)(gs + (i0 + 1) * 68 + ky0);
            float g0a[4] = {g0.x, g0.y, g0.z, g0.w};
            float g1a[4] = {g1.x, g1.y, g1.z, g1.w};
#pragma unroll
            for (int kk = 0; kk < 4; ++kk) {
                float4 dv = *(const float4*)(Dn + (ky0 + kk) * 512 + ny0);
                float da[4] = {dv.x, dv.y, dv.z, dv.w};
#pragma unroll
                for (int q = 0; q < 4; ++q) {
                    acc[q][0] += da[q] * g0a[kk];
                    acc[q][1] += da[q] * g1a[kk];
                }
            }
        }
#pragma unroll
        for (int q = 0; q < 4; ++q) {
            float2 v; v.x = acc[q][0]; v.y = acc[q][1];
            *(float2*)(outb + (size_t)(ny0 + q) * DVD + i0) = v;
        }
    }
}

extern "C" void kernel_launch(void* const* d_in, const int* in_sizes, int n_in,
                              void* d_out, int out_size, void* d_ws, size_t ws_size,
                              hipStream_t stream) {
    const float* x  = (const float*)d_in[0];
    const float* Rr = (const float*)d_in[1];
    const float* Ri = (const float*)d_in[2];
    float* out = (float*)d_out;
    float* ws  = (float*)d_ws;
    float* C   = ws + OFF_C;
    float* Fr  = ws + OFF_FR;
    float* Fi  = ws + OFF_FI;
    float* Yr  = ws + OFF_YR;
    float* Yi  = ws + OFF_YI;
    float* G   = ws + OFF_G;

    k_tables<<<128, 256, 0, stream>>>(ws);
    k_dct<<<BB * NXD, 256, 0, stream>>>(x, ws, C);
    k_rfft<<<BB * KYD, 256, 0, stream>>>(C, ws, Fr, Fi);
    k_mix<<<KXD * 4, 256, 0, stream>>>(Rr, Ri, Fr, Fi, Yr, Yi);
    k_irfft<<<BB * DVD * 2, 256, 0, stream>>>(Yr, Yi, ws, G);
    k_idct<<<BB * NXD, 256, 0, stream>>>(G, ws, out);
}

// Round 2
// 553.848 us; speedup vs baseline: 1.2102x; 1.2102x over previous
//
#include <hip/hip_runtime.h>
#include <math.h>

#define BB 4
#define NXD 512
#define NYD 512
#define DVD 32
#define KXD 64
#define KYD 64

// workspace layout (float offsets)
#define OFF_DN  0            // DtabN [64][512]
#define OFF_DT  32768        // DtabT [512][64]
#define OFF_FCN 65536        // FtcN  [64][512]
#define OFF_FSN 98304        // FtsN  [64][512]
#define OFF_FCT 131072       // FtcT  [512][64]
#define OFF_FST 163840       // FtsT  [512][64]
#define OFF_C   196608       // C  [4][64ky][512nx][32dv]
#define OFF_FR  4390912      // Fr [4][64ky][64kx][32j]
#define OFF_FI  4915200
#define OFF_YR  5439488      // Yr [4][32i][64kx][64ky]
#define OFF_YI  5963776
#define OFF_G   6488064      // G  [4][512nx][32i][64ky]
// total = 10,682,368 floats = 42.7 MB

__global__ __launch_bounds__(256) void k_tables(float* __restrict__ ws) {
    int idx = blockIdx.x * 256 + threadIdx.x;   // 0..32767
    int k = idx >> 9;                            // 0..63
    int n = idx & 511;                           // 0..511
    const float inv_sq512 = 0.04419417382415922f;  // 1/sqrt(512)
    float ak = (k == 0) ? inv_sq512 : 0.0625f;   // sqrt(2/512)=1/16
    int m = (k * (2 * n + 1)) & 2047;
    float d = ak * cospif((float)m * (1.0f / 1024.0f));
    ws[OFF_DN + k * 512 + n] = d;
    ws[OFF_DT + n * 64 + k] = d;
    int mf = (k * n) & 511;
    float c = cospif((float)mf * (1.0f / 256.0f)) * inv_sq512;
    float s = sinpif((float)mf * (1.0f / 256.0f)) * inv_sq512;
    ws[OFF_FCN + k * 512 + n] = c;
    ws[OFF_FSN + k * 512 + n] = s;
    ws[OFF_FCT + n * 64 + k] = c;
    ws[OFF_FST + n * 64 + k] = s;
}

// K1: DCT along NY, truncated.  block = (b, nx-pair); ny chunked (32KB LDS)
__global__ __launch_bounds__(256) void k_dct(const float* __restrict__ x,
                                             const float* __restrict__ ws,
                                             float* __restrict__ C) {
    __shared__ __align__(16) float xs[2][128 * 32];   // 32 KB
    int b = blockIdx.x >> 8;
    int nx = (blockIdx.x & 255) * 2;
    int t = threadIdx.x;
    int dv0 = (t & 15) * 2;
    int ky0 = (t >> 4) * 4;
    const float* Dt = ws + OFF_DT;   // [ny][64]
    float a[2][4][2] = {};
    for (int ch = 0; ch < 4; ++ch) {
        int ny0 = ch * 128;
        __syncthreads();
#pragma unroll
        for (int n = 0; n < 2; ++n) {
            const float4* src = (const float4*)(x + ((size_t)(b * NXD + nx + n) * NYD + ny0) * DVD);
            float4* dst = (float4*)xs[n];
#pragma unroll
            for (int p = 0; p < 4; ++p) dst[p * 256 + t] = src[p * 256 + t];
        }
        __syncthreads();
#pragma unroll 4
        for (int nyc = 0; nyc < 128; ++nyc) {
            float4 d4 = *(const float4*)(Dt + (ny0 + nyc) * 64 + ky0);
            float2 x0 = *(const float2*)(xs[0] + nyc * 32 + dv0);
            float2 x1 = *(const float2*)(xs[1] + nyc * 32 + dv0);
            float da[4] = {d4.x, d4.y, d4.z, d4.w};
#pragma unroll
            for (int q = 0; q < 4; ++q) {
                a[0][q][0] += da[q] * x0.x; a[0][q][1] += da[q] * x0.y;
                a[1][q][0] += da[q] * x1.x; a[1][q][1] += da[q] * x1.y;
            }
        }
    }
#pragma unroll
    for (int n = 0; n < 2; ++n)
#pragma unroll
        for (int q = 0; q < 4; ++q) {
            float2 v; v.x = a[n][q][0]; v.y = a[n][q][1];
            *(float2*)(C + ((size_t)((b * KYD + ky0 + q) * NXD + nx + n)) * DVD + dv0) = v;
        }
}

// K2: truncated rFFT along NX.  block = (b, ky, dv-half); nx chunked (16KB LDS)
__global__ __launch_bounds__(256) void k_rfft(const float* __restrict__ Cbuf,
                                              const float* __restrict__ ws,
                                              float* __restrict__ Fr,
                                              float* __restrict__ Fi) {
    __shared__ __align__(16) float cs[256 * 16];   // 16 KB
    int b = blockIdx.x >> 7;
    int r = blockIdx.x & 127;
    int ky = r >> 1;
    int dvbase = (r & 1) * 16;
    int t = threadIdx.x;
    int dv0 = (t & 7) * 2;
    int kx0 = (t >> 3) * 2;
    const float* Tc = ws + OFF_FCT;
    const float* Ts = ws + OFF_FST;
    float ar[2][2] = {}, ai[2][2] = {};
    for (int ch = 0; ch < 2; ++ch) {
        int nx0 = ch * 256;
        __syncthreads();
#pragma unroll
        for (int p = 0; p < 4; ++p) {
            int fi4 = p * 256 + t;
            int row = fi4 >> 2, c4 = fi4 & 3;
            *(float4*)(cs + row * 16 + c4 * 4) =
                *(const float4*)(Cbuf + ((size_t)(b * KYD + ky) * NXD + nx0 + row) * DVD + dvbase + c4 * 4);
        }
        __syncthreads();
#pragma unroll 4
        for (int nxc = 0; nxc < 256; ++nxc) {
            float2 cv = *(const float2*)(cs + nxc * 16 + dv0);
            float2 c2 = *(const float2*)(Tc + (nx0 + nxc) * 64 + kx0);
            float2 s2 = *(const float2*)(Ts + (nx0 + nxc) * 64 + kx0);
            ar[0][0] += c2.x * cv.x; ar[0][1] += c2.x * cv.y;
            ar[1][0] += c2.y * cv.x; ar[1][1] += c2.y * cv.y;
            ai[0][0] -= s2.x * cv.x; ai[0][1] -= s2.x * cv.y;
            ai[1][0] -= s2.y * cv.x; ai[1][1] -= s2.y * cv.y;
        }
    }
#pragma unroll
    for (int q = 0; q < 2; ++q) {
        size_t o = ((size_t)((b * KYD + ky) * KXD + kx0 + q)) * DVD + dvbase + dv0;
        float2 vr; vr.x = ar[q][0]; vr.y = ar[q][1];
        float2 vi; vi.x = ai[q][0]; vi.y = ai[q][1];
        *(float2*)(Fr + o) = vr;
        *(float2*)(Fi + o) = vi;
    }
}

// K3: channel mix per (kx, i-quad).  grid = 64*8; LDS interleaved (fr,fi) swizzled
__global__ __launch_bounds__(256) void k_mix(const float* __restrict__ Rr,
                                             const float* __restrict__ Ri,
                                             const float* __restrict__ Fr,
                                             const float* __restrict__ Fi,
                                             float* __restrict__ Yr,
                                             float* __restrict__ Yi) {
    __shared__ float fl[4 * 32 * 64 * 2];   // 64 KB, [e][j][swz(ky)]{fr,fi}
    int kx = blockIdx.x & 63;
    int ig = blockIdx.x >> 6;   // 0..7
    int t = threadIdx.x;
    int j = t & 31, kyb = t >> 5;   // kyb 0..7
#pragma unroll
    for (int e = 0; e < 4; ++e) {
#pragma unroll
        for (int p = 0; p < 8; ++p) {
            int ky = p * 8 + kyb;
            size_t go = ((size_t)((e * KYD + ky) * KXD + kx)) * DVD + j;
            int lo = ((e * 32 + j) * 64 + ((ky + j) & 63)) * 2;
            fl[lo] = Fr[go];
            fl[lo + 1] = Fi[go];
        }
    }
    __syncthreads();
    int lane = t & 63, w = t >> 6;
    int i = ig * 4 + w;
    float yr[4] = {}, yi[4] = {};
    for (int jj = 0; jj < 32; ++jj) {
        float rr = Rr[(((size_t)i * 32 + jj) * 64 + kx) * 64 + lane];
        float ri = Ri[(((size_t)i * 32 + jj) * 64 + kx) * 64 + lane];
#pragma unroll
        for (int e = 0; e < 4; ++e) {
            float2 f = *(const float2*)(fl + ((e * 32 + jj) * 64 + ((lane + jj) & 63)) * 2);
            yr[e] += rr * f.x - ri * f.y;
            yi[e] += rr * f.y + ri * f.x;
        }
    }
#pragma unroll
    for (int e = 0; e < 4; ++e) {
        size_t o = ((size_t)((e * DVD + i) * KXD + kx)) * KYD + lane;
        Yr[o] = yr[e];
        Yi[o] = yi[e];
    }
}

// K4: truncated irFFT along NX.  block = (b, i, nx-octant); grid 1024
__global__ __launch_bounds__(256) void k_irfft(const float* __restrict__ Yr,
                                               const float* __restrict__ Yi,
                                               const float* __restrict__ ws,
                                               float* __restrict__ G) {
    __shared__ __align__(16) float ylr[64 * 64];   // 16 KB [kx][ky], pre-weighted
    __shared__ __align__(16) float yli[64 * 64];
    int blk = blockIdx.x;
    int oct = blk & 7;
    int i = (blk >> 3) & 31;
    int b = blk >> 8;
    int t = threadIdx.x;
    size_t ybase = ((size_t)(b * DVD + i)) * KXD * KYD;
#pragma unroll
    for (int p = 0; p < 16; ++p) {
        int idx = p * 256 + t;
        float wk = (idx < 64) ? 1.0f : 2.0f;   // kx==0 weight 1, else 2
        ylr[idx] = Yr[ybase + idx] * wk;
        yli[idx] = Yi[ybase + idx] * wk;
    }
    __syncthreads();
    int kyg = t & 15, nxg = t >> 4;
    int ky0 = kyg * 4;
    int gnx0 = oct * 64 + nxg * 4;
    const float* Tc = ws + OFF_FCN;   // [kx][nx]
    const float* Ts = ws + OFF_FSN;
    float acc[4][4] = {};
    for (int kx = 0; kx < 64; ++kx) {
        float4 cv = *(const float4*)(Tc + kx * 512 + gnx0);
        float4 sv = *(const float4*)(Ts + kx * 512 + gnx0);
        float4 vr = *(const float4*)(ylr + kx * 64 + ky0);
        float4 vi = *(const float4*)(yli + kx * 64 + ky0);
        float ca[4] = {cv.x, cv.y, cv.z, cv.w};
        float sa[4] = {sv.x, sv.y, sv.z, sv.w};
        float ra[4] = {vr.x, vr.y, vr.z, vr.w};
        float ia[4] = {vi.x, vi.y, vi.z, vi.w};
#pragma unroll
        for (int q = 0; q < 4; ++q)
#pragma unroll
            for (int kk = 0; kk < 4; ++kk)
                acc[q][kk] += ca[q] * ra[kk] - sa[q] * ia[kk];
    }
#pragma unroll
    for (int q = 0; q < 4; ++q) {
        float4 v; v.x = acc[q][0]; v.y = acc[q][1]; v.z = acc[q][2]; v.w = acc[q][3];
        *(float4*)(G + (((size_t)(b * NXD + gnx0 + q)) * DVD + i) * KYD + ky0) = v;
    }
}

// K5: iDCT along NY.  block = (b,nx)  (unchanged control)
__global__ __launch_bounds__(256) void k_idct(const float* __restrict__ G,
                                              const float* __restrict__ ws,
                                              float* __restrict__ out) {
    __shared__ __align__(16) float gs[DVD * 68];   // [i][ky] padded to 68
    int b = blockIdx.x >> 9;
    int nx = blockIdx.x & 511;
    int t = threadIdx.x;
    const float* src = G + ((size_t)(b * NXD + nx)) * DVD * KYD;
#pragma unroll
    for (int p = 0; p < 8; ++p) {
        int idx = p * 256 + t;
        gs[(idx >> 6) * 68 + (idx & 63)] = src[idx];
    }
    __syncthreads();
    int ig = t & 15, nyg = t >> 4;
    int i0 = ig * 2;
    const float* Dn = ws + OFF_DN;   // [ky][ny]
    float* outb = out + ((size_t)(b * NXD + nx)) * NYD * DVD;
    for (int c = 0; c < 8; ++c) {
        int ny0 = c * 64 + nyg * 4;
        float acc[4][2] = {};
        for (int kyc = 0; kyc < 16; ++kyc) {
            int ky0 = kyc * 4;
            float4 g0 = *(const float4*)(gs + i0 * 68 + ky0);
            float4 g1 = *(const float4*)(gs + (i0 + 1) * 68 + ky0);
            float g0a[4] = {g0.x, g0.y, g0.z, g0.w};
            float g1a[4] = {g1.x, g1.y, g1.z, g1.w};
#pragma unroll
            for (int kk = 0; kk < 4; ++kk) {
                float4 dv = *(const float4*)(Dn + (ky0 + kk) * 512 + ny0);
                float da[4] = {dv.x, dv.y, dv.z, dv.w};
#pragma unroll
                for (int q = 0; q < 4; ++q) {
                    acc[q][0] += da[q] * g0a[kk];
                    acc[q][1] += da[q] * g1a[kk];
                }
            }
        }
#pragma unroll
        for (int q = 0; q < 4; ++q) {
            float2 v; v.x = acc[q][0]; v.y = acc[q][1];
            *(float2*)(outb + (size_t)(ny0 + q) * DVD + i0) = v;
        }
    }
}

extern "C" void kernel_launch(void* const* d_in, const int* in_sizes, int n_in,
                              void* d_out, int out_size, void* d_ws, size_t ws_size,
                              hipStream_t stream) {
    const float* x  = (const float*)d_in[0];
    const float* Rr = (const float*)d_in[1];
    const float* Ri = (const float*)d_in[2];
    float* out = (float*)d_out;
    float* ws  = (float*)d_ws;
    float* C   = ws + OFF_C;
    float* Fr  = ws + OFF_FR;
    float* Fi  = ws + OFF_FI;
    float* Yr  = ws + OFF_YR;
    float* Yi  = ws + OFF_YI;
    float* G   = ws + OFF_G;

    k_tables<<<128, 256, 0, stream>>>(ws);
    k_dct<<<BB * (NXD / 2), 256, 0, stream>>>(x, ws, C);
    k_rfft<<<BB * KYD * 2, 256, 0, stream>>>(C, ws, Fr, Fi);
    k_mix<<<KXD * 8, 256, 0, stream>>>(Rr, Ri, Fr, Fi, Yr, Yi);
    k_irfft<<<BB * DVD * 8, 256, 0, stream>>>(Yr, Yi, ws, G);
    k_idct<<<BB * NXD, 256, 0, stream>>>(G, ws, out);
}

// Round 3
// 424.247 us; speedup vs baseline: 1.5799x; 1.3055x over previous
//
#include <hip/hip_runtime.h>
#include <math.h>

#define BB 4
#define NXD 512
#define NYD 512
#define DVD 32
#define KXD 64
#define KYD 64

// workspace layout (float offsets)
#define OFF_DN  0            // DtabN [64][512]
#define OFF_DT  32768        // DtabT [512][64]
#define OFF_FCN 65536        // FtcN  [64][512]
#define OFF_FSN 98304        // FtsN  [64][512]
#define OFF_FCT 131072       // FtcT  [512][64]
#define OFF_FST 163840       // FtsT  [512][64]
#define OFF_C   196608       // C  [4][64ky][512nx][32dv]
#define OFF_FR  4390912      // Fr [4][64ky][64kx][32j]
#define OFF_FI  4915200
#define OFF_YR  5439488      // Yr [4][32i][64kx][64ky]
#define OFF_YI  5963776
#define OFF_G   6488064      // G  [4][512nx][32i][64ky]
// total = 10,682,368 floats = 42.7 MB

__global__ __launch_bounds__(256) void k_tables(float* __restrict__ ws) {
    int idx = blockIdx.x * 256 + threadIdx.x;   // 0..32767
    int k = idx >> 9;                            // 0..63
    int n = idx & 511;                           // 0..511
    const float inv_sq512 = 0.04419417382415922f;  // 1/sqrt(512)
    float ak = (k == 0) ? inv_sq512 : 0.0625f;   // sqrt(2/512)=1/16
    int m = (k * (2 * n + 1)) & 2047;
    float d = ak * cospif((float)m * (1.0f / 1024.0f));
    ws[OFF_DN + k * 512 + n] = d;
    ws[OFF_DT + n * 64 + k] = d;
    int mf = (k * n) & 511;
    float c = cospif((float)mf * (1.0f / 256.0f)) * inv_sq512;
    float s = sinpif((float)mf * (1.0f / 256.0f)) * inv_sq512;
    ws[OFF_FCN + k * 512 + n] = c;
    ws[OFF_FSN + k * 512 + n] = s;
    ws[OFF_FCT + n * 64 + k] = c;
    ws[OFF_FST + n * 64 + k] = s;
}

// K1: DCT along NY, truncated.  block = (b, nx-pair); ny chunked 64;
// D-table chunk staged in LDS (was global per-iter reads).
__global__ __launch_bounds__(256) void k_dct(const float* __restrict__ x,
                                             const float* __restrict__ ws,
                                             float* __restrict__ C) {
    __shared__ __align__(16) float xs[2][64 * 32];   // 16 KB
    __shared__ __align__(16) float dt[64 * 64];      // 16 KB
    int b = blockIdx.x >> 8;
    int nx = (blockIdx.x & 255) * 2;
    int t = threadIdx.x;
    int dv0 = (t & 15) * 2;
    int ky0 = (t >> 4) * 4;
    const float* Dt = ws + OFF_DT;   // [ny][64]
    float a[2][4][2] = {};
    for (int ch = 0; ch < 8; ++ch) {
        int ny0 = ch * 64;
        __syncthreads();
#pragma unroll
        for (int n = 0; n < 2; ++n) {
            const float4* src = (const float4*)(x + ((size_t)(b * NXD + nx + n) * NYD + ny0) * DVD);
            float4* dst = (float4*)xs[n];
#pragma unroll
            for (int p = 0; p < 2; ++p) dst[p * 256 + t] = src[p * 256 + t];
        }
        {
            const float4* src = (const float4*)(Dt + ny0 * 64);
            float4* dst = (float4*)dt;
#pragma unroll
            for (int p = 0; p < 4; ++p) dst[p * 256 + t] = src[p * 256 + t];
        }
        __syncthreads();
#pragma unroll 4
        for (int nyc = 0; nyc < 64; ++nyc) {
            float4 d4 = *(const float4*)(dt + nyc * 64 + ky0);
            float2 x0 = *(const float2*)(xs[0] + nyc * 32 + dv0);
            float2 x1 = *(const float2*)(xs[1] + nyc * 32 + dv0);
            float da[4] = {d4.x, d4.y, d4.z, d4.w};
#pragma unroll
            for (int q = 0; q < 4; ++q) {
                a[0][q][0] += da[q] * x0.x; a[0][q][1] += da[q] * x0.y;
                a[1][q][0] += da[q] * x1.x; a[1][q][1] += da[q] * x1.y;
            }
        }
    }
#pragma unroll
    for (int n = 0; n < 2; ++n)
#pragma unroll
        for (int q = 0; q < 4; ++q) {
            float2 v; v.x = a[n][q][0]; v.y = a[n][q][1];
            *(float2*)(C + ((size_t)((b * KYD + ky0 + q) * NXD + nx + n)) * DVD + dv0) = v;
        }
}

// K2: truncated rFFT along NX.  block = (b, ky, dv-half); nx chunked (16KB LDS)
__global__ __launch_bounds__(256) void k_rfft(const float* __restrict__ Cbuf,
                                              const float* __restrict__ ws,
                                              float* __restrict__ Fr,
                                              float* __restrict__ Fi) {
    __shared__ __align__(16) float cs[256 * 16];   // 16 KB
    int b = blockIdx.x >> 7;
    int r = blockIdx.x & 127;
    int ky = r >> 1;
    int dvbase = (r & 1) * 16;
    int t = threadIdx.x;
    int dv0 = (t & 7) * 2;
    int kx0 = (t >> 3) * 2;
    const float* Tc = ws + OFF_FCT;
    const float* Ts = ws + OFF_FST;
    float ar[2][2] = {}, ai[2][2] = {};
    for (int ch = 0; ch < 2; ++ch) {
        int nx0 = ch * 256;
        __syncthreads();
#pragma unroll
        for (int p = 0; p < 4; ++p) {
            int fi4 = p * 256 + t;
            int row = fi4 >> 2, c4 = fi4 & 3;
            *(float4*)(cs + row * 16 + c4 * 4) =
                *(const float4*)(Cbuf + ((size_t)(b * KYD + ky) * NXD + nx0 + row) * DVD + dvbase + c4 * 4);
        }
        __syncthreads();
#pragma unroll 4
        for (int nxc = 0; nxc < 256; ++nxc) {
            float2 cv = *(const float2*)(cs + nxc * 16 + dv0);
            float2 c2 = *(const float2*)(Tc + (nx0 + nxc) * 64 + kx0);
            float2 s2 = *(const float2*)(Ts + (nx0 + nxc) * 64 + kx0);
            ar[0][0] += c2.x * cv.x; ar[0][1] += c2.x * cv.y;
            ar[1][0] += c2.y * cv.x; ar[1][1] += c2.y * cv.y;
            ai[0][0] -= s2.x * cv.x; ai[0][1] -= s2.x * cv.y;
            ai[1][0] -= s2.y * cv.x; ai[1][1] -= s2.y * cv.y;
        }
    }
#pragma unroll
    for (int q = 0; q < 2; ++q) {
        size_t o = ((size_t)((b * KYD + ky) * KXD + kx0 + q)) * DVD + dvbase + dv0;
        float2 vr; vr.x = ar[q][0]; vr.y = ar[q][1];
        float2 vi; vi.x = ai[q][0]; vi.y = ai[q][1];
        *(float2*)(Fr + o) = vr;
        *(float2*)(Fi + o) = vi;
    }
}

// K3: channel mix per (kx, i-quad).  grid = 64*8; LDS interleaved (fr,fi) swizzled
__global__ __launch_bounds__(256) void k_mix(const float* __restrict__ Rr,
                                             const float* __restrict__ Ri,
                                             const float* __restrict__ Fr,
                                             const float* __restrict__ Fi,
                                             float* __restrict__ Yr,
                                             float* __restrict__ Yi) {
    __shared__ float fl[4 * 32 * 64 * 2];   // 64 KB, [e][j][swz(ky)]{fr,fi}
    int kx = blockIdx.x & 63;
    int ig = blockIdx.x >> 6;   // 0..7
    int t = threadIdx.x;
    int j = t & 31, kyb = t >> 5;   // kyb 0..7
#pragma unroll
    for (int e = 0; e < 4; ++e) {
#pragma unroll
        for (int p = 0; p < 8; ++p) {
            int ky = p * 8 + kyb;
            size_t go = ((size_t)((e * KYD + ky) * KXD + kx)) * DVD + j;
            int lo = ((e * 32 + j) * 64 + ((ky + j) & 63)) * 2;
            fl[lo] = Fr[go];
            fl[lo + 1] = Fi[go];
        }
    }
    __syncthreads();
    int lane = t & 63, w = t >> 6;
    int i = ig * 4 + w;
    float yr[4] = {}, yi[4] = {};
    for (int jj = 0; jj < 32; ++jj) {
        float rr = Rr[(((size_t)i * 32 + jj) * 64 + kx) * 64 + lane];
        float ri = Ri[(((size_t)i * 32 + jj) * 64 + kx) * 64 + lane];
#pragma unroll
        for (int e = 0; e < 4; ++e) {
            float2 f = *(const float2*)(fl + ((e * 32 + jj) * 64 + ((lane + jj) & 63)) * 2);
            yr[e] += rr * f.x - ri * f.y;
            yi[e] += rr * f.y + ri * f.x;
        }
    }
#pragma unroll
    for (int e = 0; e < 4; ++e) {
        size_t o = ((size_t)((e * DVD + i) * KXD + kx)) * KYD + lane;
        Yr[o] = yr[e];
        Yi[o] = yi[e];
    }
}

// K4: truncated irFFT along NX.  block = (b, i, nx-octant); grid 1024
__global__ __launch_bounds__(256) void k_irfft(const float* __restrict__ Yr,
                                               const float* __restrict__ Yi,
                                               const float* __restrict__ ws,
                                               float* __restrict__ G) {
    __shared__ __align__(16) float ylr[64 * 64];   // 16 KB [kx][ky], pre-weighted
    __shared__ __align__(16) float yli[64 * 64];
    int blk = blockIdx.x;
    int oct = blk & 7;
    int i = (blk >> 3) & 31;
    int b = blk >> 8;
    int t = threadIdx.x;
    size_t ybase = ((size_t)(b * DVD + i)) * KXD * KYD;
#pragma unroll
    for (int p = 0; p < 16; ++p) {
        int idx = p * 256 + t;
        float wk = (idx < 64) ? 1.0f : 2.0f;   // kx==0 weight 1, else 2
        ylr[idx] = Yr[ybase + idx] * wk;
        yli[idx] = Yi[ybase + idx] * wk;
    }
    __syncthreads();
    int kyg = t & 15, nxg = t >> 4;
    int ky0 = kyg * 4;
    int gnx0 = oct * 64 + nxg * 4;
    const float* Tc = ws + OFF_FCN;   // [kx][nx]
    const float* Ts = ws + OFF_FSN;
    float acc[4][4] = {};
    for (int kx = 0; kx < 64; ++kx) {
        float4 cv = *(const float4*)(Tc + kx * 512 + gnx0);
        float4 sv = *(const float4*)(Ts + kx * 512 + gnx0);
        float4 vr = *(const float4*)(ylr + kx * 64 + ky0);
        float4 vi = *(const float4*)(yli + kx * 64 + ky0);
        float ca[4] = {cv.x, cv.y, cv.z, cv.w};
        float sa[4] = {sv.x, sv.y, sv.z, sv.w};
        float ra[4] = {vr.x, vr.y, vr.z, vr.w};
        float ia[4] = {vi.x, vi.y, vi.z, vi.w};
#pragma unroll
        for (int q = 0; q < 4; ++q)
#pragma unroll
            for (int kk = 0; kk < 4; ++kk)
                acc[q][kk] += ca[q] * ra[kk] - sa[q] * ia[kk];
    }
#pragma unroll
    for (int q = 0; q < 4; ++q) {
        float4 v; v.x = acc[q][0]; v.y = acc[q][1]; v.z = acc[q][2]; v.w = acc[q][3];
        *(float4*)(G + (((size_t)(b * NXD + gnx0 + q)) * DVD + i) * KYD + ky0) = v;
    }
}

// K5: iDCT along NY.  block = (b, nx-pair); D chunk staged in LDS;
// gs stride 68 (4-way alias on g-reads measured cheap: 2.4% of cycles at R2).
#define GST 68
__global__ __launch_bounds__(256) void k_idct(const float* __restrict__ G,
                                              const float* __restrict__ ws,
                                              float* __restrict__ out) {
    __shared__ __align__(16) float gs[2][32 * GST];   // 17.4 KB
    __shared__ __align__(16) float dn[64 * 64];       // 16 KB
    int b = blockIdx.x >> 8;
    int nx = (blockIdx.x & 255) * 2;
    int t = threadIdx.x;
    int ig = t & 15, nyg = t >> 4;
    int i0 = ig * 2;
    const float* Dn = ws + OFF_DN;   // [ky][512ny]
#pragma unroll
    for (int n = 0; n < 2; ++n) {
        const float4* src = (const float4*)(G + (size_t)(b * NXD + nx + n) * DVD * KYD);
#pragma unroll
        for (int p = 0; p < 2; ++p) {
            int f = p * 256 + t;           // 512 float4 = [32i][64ky]
            int i = f >> 4, ky4 = (f & 15) * 4;
            *(float4*)(gs[n] + i * GST + ky4) = src[f];
        }
    }
    float* outb = out + ((size_t)(b * NXD + nx)) * NYD * DVD;
    for (int c = 0; c < 8; ++c) {
        __syncthreads();
        {   // stage Dn chunk [64ky][64ny]
            float4* dst = (float4*)dn;
#pragma unroll
            for (int p = 0; p < 4; ++p) {
                int f = p * 256 + t;       // 1024 float4
                int ky = f >> 4, ny4 = (f & 15) * 4;
                dst[f] = *(const float4*)(Dn + ky * 512 + c * 64 + ny4);
            }
        }
        __syncthreads();
        float acc[2][4][2] = {};
#pragma unroll 2
        for (int kyc = 0; kyc < 16; ++kyc) {
            int ky0 = kyc * 4;
            float4 g00 = *(const float4*)(gs[0] + i0 * GST + ky0);
            float4 g01 = *(const float4*)(gs[0] + (i0 + 1) * GST + ky0);
            float4 g10 = *(const float4*)(gs[1] + i0 * GST + ky0);
            float4 g11 = *(const float4*)(gs[1] + (i0 + 1) * GST + ky0);
            float g0a[2][4] = {{g00.x, g00.y, g00.z, g00.w}, {g10.x, g10.y, g10.z, g10.w}};
            float g1a[2][4] = {{g01.x, g01.y, g01.z, g01.w}, {g11.x, g11.y, g11.z, g11.w}};
#pragma unroll
            for (int kk = 0; kk < 4; ++kk) {
                float4 dv = *(const float4*)(dn + (ky0 + kk) * 64 + nyg * 4);
                float da[4] = {dv.x, dv.y, dv.z, dv.w};
#pragma unroll
                for (int q = 0; q < 4; ++q) {
                    acc[0][q][0] += da[q] * g0a[0][kk];
                    acc[0][q][1] += da[q] * g1a[0][kk];
                    acc[1][q][0] += da[q] * g0a[1][kk];
                    acc[1][q][1] += da[q] * g1a[1][kk];
                }
            }
        }
        int ny0 = c * 64 + nyg * 4;
#pragma unroll
        for (int n = 0; n < 2; ++n)
#pragma unroll
            for (int q = 0; q < 4; ++q) {
                float2 v; v.x = acc[n][q][0]; v.y = acc[n][q][1];
                *(float2*)(outb + ((size_t)n * NYD + ny0 + q) * DVD + i0) = v;
            }
    }
}

extern "C" void kernel_launch(void* const* d_in, const int* in_sizes, int n_in,
                              void* d_out, int out_size, void* d_ws, size_t ws_size,
                              hipStream_t stream) {
    const float* x  = (const float*)d_in[0];
    const float* Rr = (const float*)d_in[1];
    const float* Ri = (const float*)d_in[2];
    float* out = (float*)d_out;
    float* ws  = (float*)d_ws;
    float* C   = ws + OFF_C;
    float* Fr  = ws + OFF_FR;
    float* Fi  = ws + OFF_FI;
    float* Yr  = ws + OFF_YR;
    float* Yi  = ws + OFF_YI;
    float* G   = ws + OFF_G;

    k_tables<<<128, 256, 0, stream>>>(ws);
    k_dct<<<BB * (NXD / 2), 256, 0, stream>>>(x, ws, C);
    k_rfft<<<BB * KYD * 2, 256, 0, stream>>>(C, ws, Fr, Fi);
    k_mix<<<KXD * 8, 256, 0, stream>>>(Rr, Ri, Fr, Fi, Yr, Yi);
    k_irfft<<<BB * DVD * 8, 256, 0, stream>>>(Yr, Yi, ws, G);
    k_idct<<<BB * NXD / 2, 256, 0, stream>>>(G, ws, out);
}